// Round 3
// baseline (76.268 us; speedup 1.0000x reference)
//
#include <hip/hip_runtime.h>

typedef __attribute__((ext_vector_type(8))) short short8;
typedef __attribute__((ext_vector_type(4))) float f32x4;

namespace {

// Tap table in a static device global: harness unconditionally poisons the
// full 256 MiB d_ws (~41 us fill) whether we use it or not, but the static
// global keeps conv independent of workspace semantics. Fully rewritten by
// prep_B every launch.
__device__ uint4 B2g[16384];                    // [ic*8 + ot*2 + kt][64 lanes]

__device__ __forceinline__ unsigned short f2bf(float f) {
    unsigned int u = __float_as_uint(f);
    u += 0x7fffu + ((u >> 16) & 1u);     // RNE to bf16
    return (unsigned short)(u >> 16);
}

// ---------------------------------------------------------------------------
// Unchanged (verified): lane-major fragment-coalesced taps. uint4 slot =
// (ic*8 + ot*2 + kt)*64 + lane, lane = g*16 + n. 8 bf16 taps (q flipped,
// q==7 zero) of tap-row a = 4kt+g (flipped, a==7 zero) for oc = 16*ot+n.
// ---------------------------------------------------------------------------
__global__ void prep_B(const float* __restrict__ ker) {
    int t  = blockIdx.x * 256 + threadIdx.x;   // 16384 threads
    int a  = t & 7;
    int oc = (t >> 3) & 63;
    int ic = t >> 9;
    unsigned int d[4] = {0u, 0u, 0u, 0u};
    if (a < 7) {
        const float* row = ker + ((oc * 32 + ic) * 49) + (6 - a) * 7;
        float v[8];
#pragma unroll
        for (int q = 0; q < 7; ++q) v[q] = row[6 - q];
        v[7] = 0.0f;
#pragma unroll
        for (int j = 0; j < 4; ++j)
            d[j] = (unsigned int)f2bf(v[2 * j]) | ((unsigned int)f2bf(v[2 * j + 1]) << 16);
    }
    int ot = oc >> 4, nn = oc & 15, kt = a >> 2, gg = a & 3;
    B2g[(ic * 8 + ot * 2 + kt) * 64 + gg * 16 + nn] = make_uint4(d[0], d[1], d[2], d[3]);
}

// ---------------------------------------------------------------------------
// Conv: grid 512 = b(8) x yp(32) x xh(2); block = 512 thr (8 waves).
// Stage + compute identical to R2 (wave-local stage, no barrier; 4 ic x
// 4 nt x 4 ot MFMA; abs per ic). Merge rewritten:
//   - P double-buffered: phase parity 0 -> P, 1 -> P2 (aliases dead H),
//     ONE barrier per phase (4 total, was 8). Safe: a wave at phase k+2's
//     publish passed barrier k+1, which happens-after all phase-k reads.
//   - reducer remap: thread t -> (oc = t>>3, x-pair = 2*(t&7)); two outputs
//     are x-adjacent in one oc plane -> single float2 store. Same icg
//     summation order -> bit-identical results.
// LDS stays 72 KB -> 2 blocks/CU.
// ---------------------------------------------------------------------------
__global__ __launch_bounds__(512, 4) void conv_mfma(
    const float* __restrict__ img,          // [8][32][64][64]
    float* __restrict__ out)                // [8][64][64][64]
{
    __shared__ unsigned int H[10240];       // 32 planes x 8 rows x 40 dw = 40960 B
    __shared__ float P[8192];               // 32768 B publish buffer (phase 0,2)

    const int bid  = blockIdx.x;            // b*64 + yp*2 + xh
    const int xh   = bid & 1;
    const int yp   = (bid >> 1) & 31;
    const int b    = bid >> 6;
    const int y0   = yp * 2;
    const int tid  = threadIdx.x;
    const int lane = tid & 63;
    const int w    = tid >> 6;              // 8 waves; compute role: icg = w
    const int n    = lane & 15;
    const int g    = lane >> 4;

    const float* base = img + (size_t)b * 32 * 4096;

    // ---- stage: wave w stages planes 4w..4w+3, rows (y0-2..y0+5); no barrier.
    const int colg = (32 * xh + lane - 2) & 63;
    float v[32];
#pragma unroll
    for (int j = 0; j < 32; ++j) {
        const int ic  = w * 4 + (j >> 3);
        const int row = (y0 - 2 + (j & 7)) & 63;
        v[j] = base[ic * 4096 + row * 64 + colg];
    }
#pragma unroll
    for (int j = 0; j < 32; ++j) {
        const int ic = w * 4 + (j >> 3);
        const int r  = j & 7;
        const unsigned int h  = f2bf(v[j]);
        const unsigned int hn = (unsigned int)__shfl((int)h, (lane + 1) & 63);
        if (lane < 38) H[ic * 320 + r * 40 + lane] = h | (hn << 16);
    }
    // no __syncthreads: this wave only reads planes it wrote itself

    // ---- compute: 4 ic x 4 n-tiles x 4 oc-tiles ----
    f32x4 acc[4][4];
#pragma unroll
    for (int nt = 0; nt < 4; ++nt)
#pragma unroll
        for (int ot = 0; ot < 4; ++ot) acc[nt][ot] = (f32x4){0.f, 0.f, 0.f, 0.f};

#pragma unroll 1
    for (int ici = 0; ici < 4; ++ici) {
        const int ic = w * 4 + ici;
        uint4 bf[8];                              // q = ot*2 + kt
#pragma unroll
        for (int q = 0; q < 8; ++q)
            bf[q] = B2g[(ic * 8 + q) * 64 + lane];

#pragma unroll
        for (int nt = 0; nt < 4; ++nt) {          // ry = nt>>1, mt = nt&1
            const int ry = nt >> 1;
            const int s0 = 16 * (nt & 1) + n;     // slot = x_local -> cols x-2..x+5
            const int r0 = ry + g;                // tap row a = g (kt=0)
            int r1 = r0 + 4;                      // tap row a = g+4 (kt=1)
            if (r1 > 7) r1 = 7;                   // only g==3 (zero taps)
            const int d0 = ic * 320 + r0 * 40 + s0;
            const int d1 = ic * 320 + r1 * 40 + s0;
            uint4 i0 = make_uint4(H[d0], H[d0 + 2], H[d0 + 4], H[d0 + 6]);
            uint4 i1 = make_uint4(H[d1], H[d1 + 2], H[d1 + 4], H[d1 + 6]);
            short8 f0 = __builtin_bit_cast(short8, i0);
            short8 f1 = __builtin_bit_cast(short8, i1);
#pragma unroll
            for (int ot = 0; ot < 4; ++ot) {
                f32x4 d = (f32x4){0.f, 0.f, 0.f, 0.f};
                d = __builtin_amdgcn_mfma_f32_16x16x32_bf16(
                        __builtin_bit_cast(short8, bf[2 * ot]),     f0, d, 0, 0, 0);
                d = __builtin_amdgcn_mfma_f32_16x16x32_bf16(
                        __builtin_bit_cast(short8, bf[2 * ot + 1]), f1, d, 0, 0, 0);
#pragma unroll
                for (int i = 0; i < 4; ++i)
                    acc[nt][ot][i] += __builtin_fabsf(d[i]);
            }
        }
    }

    // ---- merge + store: 4 phases, ONE barrier each, double-buffered P ----
    // publish element (icg=w, ot, g, n, i) at region (i>>1)*4096 +
    // (icg*4+ot)*128 + g*32 + n*2 + (i&1).
    float* P2 = (float*)H;                        // H is dead after compute
    const int oc_r = tid >> 3;                    // reducer: oc plane
    const int xp   = 2 * (tid & 7);               // reducer: x pair (even)
    const int rot  = oc_r >> 4;
    const int rg   = (oc_r >> 2) & 3;
    const int ri   = oc_r & 3;
    const int rbase = (ri >> 1) * 4096 + rot * 128 + rg * 32 + xp * 2 + (ri & 1);
    float* o = out + (size_t)b * 64 * 4096;
#pragma unroll
    for (int nt = 0; nt < 4; ++nt) {
        float* Pb = (nt & 1) ? P2 : P;
        // publish (phase 0 may overlap other waves' compute reads of H: P only;
        // phases >=1 write P2=H only after barrier 0, when all compute is done)
#pragma unroll
        for (int ot = 0; ot < 4; ++ot) {
            const int idx = (w * 4 + ot) * 128 + lane * 2;
            Pb[idx]            = acc[nt][ot][0];
            Pb[idx + 1]        = acc[nt][ot][1];
            Pb[4096 + idx]     = acc[nt][ot][2];
            Pb[4096 + idx + 1] = acc[nt][ot][3];
        }
        __syncthreads();
        // reduce 8-way over icg + store one float2
        {
            float s0 = 0.f, s1 = 0.f;
#pragma unroll
            for (int icg = 0; icg < 8; ++icg) {
                const int idx = rbase + icg * 512;
                s0 += Pb[idx];
                s1 += Pb[idx + 2];
            }
            const int y  = y0 + (nt >> 1);
            const int xb = 32 * xh + 16 * (nt & 1) + xp;
            *(float2*)&o[(size_t)oc_r * 4096 + y * 64 + xb] = make_float2(s0, s1);
        }
        // no trailing barrier: next phase writes the OTHER buffer; reuse of
        // this buffer (phase nt+2) is fenced by barrier nt+1.
    }
}

} // namespace

extern "C" void kernel_launch(void* const* d_in, const int* in_sizes, int n_in,
                              void* d_out, int out_size, void* d_ws, size_t ws_size,
                              hipStream_t stream) {
    const float* img = (const float*)d_in[0];   // [8][32][64][64]
    const float* ker = (const float*)d_in[1];   // [64][32][7][7]
    float* out = (float*)d_out;                 // [8][64][64][64]
    (void)d_ws; (void)ws_size;                  // workspace deliberately unused

    prep_B<<<dim3(64), dim3(256), 0, stream>>>(ker);
    conv_mfma<<<dim3(512), dim3(512), 0, stream>>>(img, out);
}

// Round 4
// 74.393 us; speedup vs baseline: 1.0252x; 1.0252x over previous
//
#include <hip/hip_runtime.h>

typedef __attribute__((ext_vector_type(8))) short short8;
typedef __attribute__((ext_vector_type(4))) float f32x4;

namespace {

__device__ __forceinline__ unsigned short f2bf(float f) {
    unsigned int u = __float_as_uint(f);
    u += 0x7fffu + ((u >> 16) & 1u);     // RNE to bf16
    return (unsigned short)(u >> 16);
}

// ---------------------------------------------------------------------------
// B2: lane-major fragment-coalesced taps. uint4 slot = (ic*8 + ot*2 + kt)*64 + lane,
// lane = g*16 + n. 8 bf16 taps (q flipped, q==7 zero) of tap-row a = 4kt+g
// (flipped, a==7 zero) for oc = 16*ot+n. One wave B-frag load = one coalesced
// 1 KB global_load_dwordx4.
// ---------------------------------------------------------------------------
__global__ void prep_B(const float* __restrict__ ker, uint4* __restrict__ B2) {
    int t  = blockIdx.x * 256 + threadIdx.x;   // 16384 threads
    int a  = t & 7;
    int oc = (t >> 3) & 63;
    int ic = t >> 9;
    unsigned int d[4] = {0u, 0u, 0u, 0u};
    if (a < 7) {
        const float* row = ker + ((oc * 32 + ic) * 49) + (6 - a) * 7;
        float v[8];
#pragma unroll
        for (int q = 0; q < 7; ++q) v[q] = row[6 - q];
        v[7] = 0.0f;
#pragma unroll
        for (int j = 0; j < 4; ++j)
            d[j] = (unsigned int)f2bf(v[2 * j]) | ((unsigned int)f2bf(v[2 * j + 1]) << 16);
    }
    int ot = oc >> 4, n = oc & 15, kt = a >> 2, g = a & 3;
    B2[(ic * 8 + ot * 2 + kt) * 64 + g * 16 + n] = make_uint4(d[0], d[1], d[2], d[3]);
}

// ---------------------------------------------------------------------------
// Conv: grid 256 = b(8) x rowpair(32); block = 1024 thr (16 waves), computes
// 2 output rows x 64 x x 64 oc over ALL 32 ic. Waves: xh = w&1 (32-px half),
// icg = w>>1 (4-ic group). Per ic a wave loads 8 tap-frags and fires 32 MFMAs
// (4 n-tiles x 4 oc-tiles) -> taps amortized 2x vs R7; img-frag LDS reads
// unchanged. 8 icg-partials merged by an in-LDS tree; plain coalesced stores.
// H (pitch 72, plane stride 576): dword p = pack(bf16 col (p-2)%64, (p-1)%64),
// window row r = img row (y0-2+r)%64, r in [0,8); r==8 (a==7,ry==1) reads the
// next plane / zeroed pad - killed by zero B columns.
// ---------------------------------------------------------------------------
__global__ __launch_bounds__(1024, 4) void conv_mfma(
    const float* __restrict__ img,          // [8][32][64][64]
    const uint4* __restrict__ B2,           // prepped taps
    float* __restrict__ out)                // [8][64][64][64]
{
    __shared__ unsigned int H[18576];       // 32*576 + 144 pad = 74304 B

    const int bid  = blockIdx.x;            // b*32 + yp
    const int yp   = bid & 31;
    const int b    = bid >> 5;
    const int y0   = yp * 2;
    const int tid  = threadIdx.x;
    const int lane = tid & 63;
    const int w    = tid >> 6;              // 16 waves
    const int xh   = w & 1;
    const int icg  = w >> 1;                // 0..7, 4 ic each
    const int n    = lane & 15;
    const int g    = lane >> 4;

    const float* base = img + (size_t)b * 32 * 4096;

    // ---- zero the pad rows (read by plane-31 a==7) ----
    if (tid < 144) H[18432 + tid] = 0u;

    // ---- stage: wave w owns planes 2w, 2w+1, 8 rows each; col = lane ----
    float v[16];
#pragma unroll
    for (int j = 0; j < 16; ++j) {
        const int pl  = 2 * w + (j >> 3);
        const int row = (y0 - 2 + (j & 7)) & 63;
        v[j] = base[pl * 4096 + row * 64 + lane];
    }
#pragma unroll
    for (int j = 0; j < 16; ++j) {
        const int pl = 2 * w + (j >> 3);
        const int r  = j & 7;
        const unsigned int h  = f2bf(v[j]);
        const unsigned int hn = (unsigned int)__shfl((int)h, (lane + 1) & 63);
        const unsigned int dw = h | (hn << 16);   // cols (lane, lane+1) -> dword lane+2
        const int idx = pl * 576 + r * 72;
        H[idx + lane + 2] = dw;
        if (lane >= 62) H[idx + lane - 62] = dw;  // wrap left  (p = 0,1)
        if (lane <= 5)  H[idx + lane + 66] = dw;  // wrap right (p = 66..71)
    }
    __syncthreads();

    // ---- compute: 4 ic x 4 n-tiles x 4 oc-tiles ----
    f32x4 acc[4][4];
#pragma unroll
    for (int nt = 0; nt < 4; ++nt)
#pragma unroll
        for (int ot = 0; ot < 4; ++ot) acc[nt][ot] = (f32x4){0.f, 0.f, 0.f, 0.f};

#pragma unroll 1
    for (int ici = 0; ici < 4; ++ici) {
        const int ic = icg * 4 + ici;
        uint4 bf[8];                              // q = ot*2 + kt
#pragma unroll
        for (int q = 0; q < 8; ++q)
            bf[q] = B2[(ic * 8 + q) * 64 + lane];

#pragma unroll
        for (int nt = 0; nt < 4; ++nt) {          // ry = nt>>1, mt = nt&1
            const int b0 = ic * 576 + ((nt >> 1) + g) * 72 + 32 * xh + 16 * (nt & 1) + n;
            const int b1 = b0 + 288;              // tap row a = g+4
            uint4 i0 = make_uint4(H[b0], H[b0 + 2], H[b0 + 4], H[b0 + 6]);
            uint4 i1 = make_uint4(H[b1], H[b1 + 2], H[b1 + 4], H[b1 + 6]);
            short8 f0 = __builtin_bit_cast(short8, i0);
            short8 f1 = __builtin_bit_cast(short8, i1);
#pragma unroll
            for (int ot = 0; ot < 4; ++ot) {
                f32x4 d = (f32x4){0.f, 0.f, 0.f, 0.f};
                d = __builtin_amdgcn_mfma_f32_16x16x32_bf16(
                        __builtin_bit_cast(short8, bf[2 * ot]),     f0, d, 0, 0, 0);
                d = __builtin_amdgcn_mfma_f32_16x16x32_bf16(
                        __builtin_bit_cast(short8, bf[2 * ot + 1]), f1, d, 0, 0, 0);
#pragma unroll
                for (int i = 0; i < 4; ++i)
                    acc[nt][ot][i] += __builtin_fabsf(d[i]);
            }
        }
    }

    // ---- 8-way icg merge via LDS tree (aliases dead H); conflict-free ----
    float* P = (float*)H;
    __syncthreads();                              // compute done reading H

    // Round A (distance 4), sub-phased by nt-half to fit LDS.
#pragma unroll
    for (int ph = 0; ph < 2; ++ph) {
        if (icg >= 4) {                           // publish nt in {2ph, 2ph+1}
            const int rb = ((icg - 4) * 2 + xh) * 2048;
#pragma unroll
            for (int nh = 0; nh < 2; ++nh) {
                const int nt = 2 * ph + nh;
                float* q = P + rb + (nh * 4 + 0) * 256 + lane * 4;
#pragma unroll
                for (int ot = 0; ot < 4; ++ot)
#pragma unroll
                    for (int i = 0; i < 4; ++i)
                        P[rb + (nh * 4 + ot) * 256 + lane * 4 + i] = acc[nt][ot][i];
                (void)q;
            }
        }
        __syncthreads();
        if (icg < 4) {                            // absorb
            const int rb = (icg * 2 + xh) * 2048;
#pragma unroll
            for (int nh = 0; nh < 2; ++nh) {
                const int nt = 2 * ph + nh;
#pragma unroll
                for (int ot = 0; ot < 4; ++ot)
#pragma unroll
                    for (int i = 0; i < 4; ++i)
                        acc[nt][ot][i] += P[rb + (nh * 4 + ot) * 256 + lane * 4 + i];
            }
        }
        __syncthreads();
    }
    // Round B (distance 2): icg 2,3 publish full acc.
    if (icg == 2 || icg == 3) {
        const int rb = ((icg - 2) * 2 + xh) * 4096;
#pragma unroll
        for (int nt = 0; nt < 4; ++nt)
#pragma unroll
            for (int ot = 0; ot < 4; ++ot)
#pragma unroll
                for (int i = 0; i < 4; ++i)
                    P[rb + (nt * 4 + ot) * 256 + lane * 4 + i] = acc[nt][ot][i];
    }
    __syncthreads();
    if (icg == 0 || icg == 1) {
        const int rb = (icg * 2 + xh) * 4096;
#pragma unroll
        for (int nt = 0; nt < 4; ++nt)
#pragma unroll
            for (int ot = 0; ot < 4; ++ot)
#pragma unroll
                for (int i = 0; i < 4; ++i)
                    acc[nt][ot][i] += P[rb + (nt * 4 + ot) * 256 + lane * 4 + i];
    }
    __syncthreads();
    // Round C (distance 1): icg 1 publishes.
    if (icg == 1) {
        const int rb = xh * 4096;
#pragma unroll
        for (int nt = 0; nt < 4; ++nt)
#pragma unroll
            for (int ot = 0; ot < 4; ++ot)
#pragma unroll
                for (int i = 0; i < 4; ++i)
                    P[rb + (nt * 4 + ot) * 256 + lane * 4 + i] = acc[nt][ot][i];
    }
    __syncthreads();
    if (icg == 0) {                               // final absorb + store
        const int rb = xh * 4096;
        float* o = out + (size_t)b * 64 * 4096;
#pragma unroll
        for (int nt = 0; nt < 4; ++nt) {
            const int y  = y0 + (nt >> 1);
            const int x0 = 32 * xh + 16 * (nt & 1);
#pragma unroll
            for (int ot = 0; ot < 4; ++ot)
#pragma unroll
                for (int i = 0; i < 4; ++i) {
                    const int oc = 16 * ot + 4 * g + i;
                    o[(size_t)oc * 4096 + y * 64 + x0 + n] =
                        acc[nt][ot][i] + P[rb + (nt * 4 + ot) * 256 + lane * 4 + i];
                }
        }
    }
}

} // namespace

extern "C" void kernel_launch(void* const* d_in, const int* in_sizes, int n_in,
                              void* d_out, int out_size, void* d_ws, size_t ws_size,
                              hipStream_t stream) {
    const float* img = (const float*)d_in[0];   // [8][32][64][64]
    const float* ker = (const float*)d_in[1];   // [64][32][7][7]
    float* out = (float*)d_out;                 // [8][64][64][64]
    uint4* B2 = (uint4*)d_ws;                   // 256 KB lane-major taps

    prep_B<<<dim3(64), dim3(256), 0, stream>>>(ker, B2);
    conv_mfma<<<dim3(256), dim3(1024), 0, stream>>>(img, B2, out);
}